// Round 1
// baseline (432.666 us; speedup 1.0000x reference)
//
#include <hip/hip_runtime.h>
#include <hip/hip_bf16.h>

#define B_  2
#define S_  2048
#define H_  1024
#define NH_ 16
#define HD_ 64
#define T_  (B_*S_)     // 4096 tokens
#define H3_ (3*H_)      // 3072

typedef float  floatx4 __attribute__((ext_vector_type(4)));
typedef __bf16 bf16x8  __attribute__((ext_vector_type(8)));

__device__ inline unsigned short f2bf_rn(float f) {
    union { float f; unsigned int u; } v; v.f = f;
    unsigned int u = v.u;
    u += 0x7fffu + ((u >> 16) & 1u);
    return (unsigned short)(u >> 16);
}
__device__ inline float bf2f(unsigned short h) {
    union { unsigned int u; float f; } v; v.u = ((unsigned int)h) << 16;
    return v.f;
}
__device__ inline floatx4 fzero4() { floatx4 v; v[0]=0.f; v[1]=0.f; v[2]=0.f; v[3]=0.f; return v; }

// ---------------------------------------------------------------- fp32 -> bf16 cast
__global__ __launch_bounds__(256) void cvt_bf16_k(const float* __restrict__ src,
                                                  unsigned short* __restrict__ dst, int n) {
    int i = (blockIdx.x * 256 + threadIdx.x) * 4;
    if (i < n) {
        float4 v = *reinterpret_cast<const float4*>(src + i);
        ushort4 o = make_ushort4(f2bf_rn(v.x), f2bf_rn(v.y), f2bf_rn(v.z), f2bf_rn(v.w));
        *reinterpret_cast<ushort4*>(dst + i) = o;
    }
}

// ---------------------------------------------------------------- LayerNorm (fp32 stats, bf16 out)
__global__ __launch_bounds__(256) void layernorm_k(const float* __restrict__ x,
                                                   const float* __restrict__ w,
                                                   const float* __restrict__ b,
                                                   unsigned short* __restrict__ xn) {
    const int t   = blockIdx.x;
    const int tid = threadIdx.x;
    const float4 v = reinterpret_cast<const float4*>(x + (size_t)t * H_)[tid];
    float s  = v.x + v.y + v.z + v.w;
    float s2 = v.x*v.x + v.y*v.y + v.z*v.z + v.w*v.w;
    for (int off = 32; off > 0; off >>= 1) {
        s  += __shfl_down(s,  off, 64);
        s2 += __shfl_down(s2, off, 64);
    }
    __shared__ float red[8];
    const int wave = tid >> 6, lane = tid & 63;
    if (lane == 0) { red[wave] = s; red[4 + wave] = s2; }
    __syncthreads();
    if (tid == 0) {
        red[0] = red[0] + red[1] + red[2] + red[3];
        red[4] = red[4] + red[5] + red[6] + red[7];
    }
    __syncthreads();
    const float mean = red[0] * (1.f / H_);
    const float var  = red[4] * (1.f / H_) - mean * mean;
    const float rstd = rsqrtf(var + 1e-5f);
    const float4 wv = reinterpret_cast<const float4*>(w)[tid];
    const float4 bv = reinterpret_cast<const float4*>(b)[tid];
    ushort4 o = make_ushort4(f2bf_rn((v.x - mean) * rstd * wv.x + bv.x),
                             f2bf_rn((v.y - mean) * rstd * wv.y + bv.y),
                             f2bf_rn((v.z - mean) * rstd * wv.z + bv.z),
                             f2bf_rn((v.w - mean) * rstd * wv.w + bv.w));
    reinterpret_cast<ushort4*>(xn + (size_t)t * H_)[tid] = o;
}

// ---------------------------------------------------------------- bf16 MFMA GEMM  C = A(MxK) @ B(KxN) + bias
// 128x128 block tile, BK=32, 4 waves as 2x2 of 64x64 wave tiles, 4x4 16x16x32 MFMA per wave.
#define BM 128
#define BN 128
#define BK 32
#define LDT 40   // padded LDS stride (elements): 80B = 5 superbanks (odd -> 2-way free), 16B aligned

template <bool OUT_F32>
__global__ __launch_bounds__(256, 2) void gemm_bf16(const unsigned short* __restrict__ A,
                                                    const unsigned short* __restrict__ Bm,
                                                    const float* __restrict__ bias,
                                                    float* __restrict__ Cf,
                                                    unsigned short* __restrict__ Cb,
                                                    int M, int N, int K) {
    __shared__ unsigned short As[BM * LDT];
    __shared__ unsigned short Bs[BN * LDT];   // stored transposed: Bs[n][k]

    const int tid  = threadIdx.x;
    const int lane = tid & 63;
    const int wave = tid >> 6;
    const int wr = wave >> 1, wc = wave & 1;
    const int mBase = blockIdx.y * BM;
    const int nBase = blockIdx.x * BN;

    floatx4 acc[4][4];
    #pragma unroll
    for (int i = 0; i < 4; i++)
        #pragma unroll
        for (int j = 0; j < 4; j++) acc[i][j] = fzero4();

    const int arow = tid >> 2;        // 0..63
    const int acol = (tid & 3) * 8;   // 0,8,16,24
    const int bk   = tid >> 4;        // 0..15
    const int bn   = (tid & 15) * 8;  // 0..120

    const int mrow = lane & 15;
    const int koff = (lane >> 4) * 8;

    for (int kb = 0; kb < K; kb += BK) {
        #pragma unroll
        for (int p = 0; p < 2; p++) {     // A tile: 128x32, k-contiguous
            const int r = arow + p * 64;
            const uint4 v = *reinterpret_cast<const uint4*>(&A[(size_t)(mBase + r) * K + kb + acol]);
            *reinterpret_cast<uint4*>(&As[r * LDT + acol]) = v;
        }
        #pragma unroll
        for (int p = 0; p < 2; p++) {     // B tile: 32x128 -> transposed scatter Bs[n][k]
            const int kk = bk + p * 16;
            uint4 v = *reinterpret_cast<const uint4*>(&Bm[(size_t)(kb + kk) * N + nBase + bn]);
            const unsigned short* e = reinterpret_cast<const unsigned short*>(&v);
            #pragma unroll
            for (int j = 0; j < 8; j++) { // rotate write order to spread banks
                const int i = (j + (tid & 7)) & 7;
                Bs[(bn + i) * LDT + kk] = e[i];
            }
        }
        __syncthreads();

        bf16x8 afrag[4], bfrag[4];
        #pragma unroll
        for (int mt = 0; mt < 4; mt++)
            afrag[mt] = *reinterpret_cast<const bf16x8*>(&As[(wr * 64 + mt * 16 + mrow) * LDT + koff]);
        #pragma unroll
        for (int nt = 0; nt < 4; nt++)
            bfrag[nt] = *reinterpret_cast<const bf16x8*>(&Bs[(wc * 64 + nt * 16 + mrow) * LDT + koff]);
        #pragma unroll
        for (int mt = 0; mt < 4; mt++)
            #pragma unroll
            for (int nt = 0; nt < 4; nt++)
                acc[mt][nt] = __builtin_amdgcn_mfma_f32_16x16x32_bf16(afrag[mt], bfrag[nt], acc[mt][nt], 0, 0, 0);
        __syncthreads();
    }

    // epilogue: C/D layout col=lane&15, row=(lane>>4)*4+reg
    const int col0 = lane & 15;
    const int r0   = (lane >> 4) * 4;
    #pragma unroll
    for (int mt = 0; mt < 4; mt++) {
        #pragma unroll
        for (int nt = 0; nt < 4; nt++) {
            const int gcol = nBase + wc * 64 + nt * 16 + col0;
            const float bs = bias[gcol];
            #pragma unroll
            for (int reg = 0; reg < 4; reg++) {
                const int grow = mBase + wr * 64 + mt * 16 + r0 + reg;
                const float v = acc[mt][nt][reg] + bs;
                if constexpr (OUT_F32) Cf[(size_t)grow * N + gcol] = v;
                else                   Cb[(size_t)grow * N + gcol] = f2bf_rn(v);
            }
        }
    }
}

// ---------------------------------------------------------------- rotary + scatter qkv -> Q/K/V [b,h,s,d] bf16
__global__ __launch_bounds__(256) void rotary_scatter_k(const unsigned short* __restrict__ qkv,
                                                        unsigned short* __restrict__ Q,
                                                        unsigned short* __restrict__ K,
                                                        unsigned short* __restrict__ V) {
    const int t   = blockIdx.x;           // token
    const int b   = t / S_;
    const int s   = t % S_;
    const int tid = threadIdx.x;
    const unsigned short* row = qkv + (size_t)t * H3_;
    #pragma unroll
    for (int i = 0; i < 4; i++) {
        const int idx = tid + i * 256;    // 0..1023 = h*64 + d
        const int h = idx >> 6, d = idx & 63;
        const int j = d & 31;
        const float inv_freq = powf(10000.f, -(float)j * (1.f / 32.f));
        const float fr = (float)s * inv_freq;
        const float cs = cosf(fr), sn = sinf(fr);
        const size_t dst = ((size_t)(b * NH_ + h) * S_ + s) * HD_ + d;
        // q
        {
            const float val = bf2f(row[idx]);
            const float par = bf2f(row[idx ^ 32]);
            const float rot = (d < 32) ? -par : par;
            Q[dst] = f2bf_rn(val * cs + rot * sn);
        }
        // k
        {
            const float val = bf2f(row[H_ + idx]);
            const float par = bf2f(row[H_ + (idx ^ 32)]);
            const float rot = (d < 32) ? -par : par;
            K[dst] = f2bf_rn(val * cs + rot * sn);
        }
        // v passthrough
        V[dst] = row[2 * H_ + idx];
    }
}

// ---------------------------------------------------------------- flash attention (causal + mask bias)
// grid (S/64 q-tiles, B*NH). block 256 = 4 waves; wave owns 16 q-rows. K-tiles of 64 keys.
#define ALD 72   // 144B stride: 9 superbanks (odd) -> conflict-free-ish b128

__global__ __launch_bounds__(256, 2) void attn_k(const unsigned short* __restrict__ Q,
                                                 const unsigned short* __restrict__ K,
                                                 const unsigned short* __restrict__ V,
                                                 const int* __restrict__ mask,
                                                 unsigned short* __restrict__ ctx) {
    const int qt  = blockIdx.x;
    const int bh  = blockIdx.y;
    const int b   = bh >> 4;
    const int h   = bh & 15;
    const int tid = threadIdx.x;
    const int lane = tid & 63;
    const int wave = tid >> 6;

    __shared__ unsigned short Ks[64 * ALD];         // [key][hd]
    __shared__ unsigned short Vts[64 * ALD];        // [hd][key]  (transposed)
    __shared__ unsigned short Ps[4][16 * ALD];      // per-wave P round-trip
    __shared__ float mb[64];

    const size_t base  = (size_t)bh * S_ * HD_;
    const int qrow0 = qt * 64 + wave * 16;
    const int mrow  = lane & 15;
    const int koff  = (lane >> 4) * 8;
    const int r0    = (lane >> 4) * 4;
    const int col0  = lane & 15;

    // Q fragments (A-operand) straight from global
    bf16x8 qfrag0 = *reinterpret_cast<const bf16x8*>(&Q[base + (size_t)(qrow0 + mrow) * HD_ + koff]);
    bf16x8 qfrag1 = *reinterpret_cast<const bf16x8*>(&Q[base + (size_t)(qrow0 + mrow) * HD_ + 32 + koff]);

    floatx4 Oacc[4];
    #pragma unroll
    for (int i = 0; i < 4; i++) Oacc[i] = fzero4();
    float m_i[4], l_i[4];
    #pragma unroll
    for (int r = 0; r < 4; r++) { m_i[r] = -1e30f; l_i[r] = 0.f; }

    for (int kt = 0; kt <= qt; kt++) {
        const int kb = kt * 64;
        // ---- stage K [key][hd]
        {
            const int r = tid >> 2;
            #pragma unroll
            for (int p = 0; p < 2; p++) {
                const int c = (tid & 3) * 8 + p * 32;
                const uint4 v = *reinterpret_cast<const uint4*>(&K[base + (size_t)(kb + r) * HD_ + c]);
                *reinterpret_cast<uint4*>(&Ks[r * ALD + c]) = v;
            }
        }
        // ---- stage V transposed [hd][key]
        {
            const int d8 = (tid & 7) * 8;
            #pragma unroll
            for (int p = 0; p < 2; p++) {
                const int key = (tid >> 3) + p * 32;
                uint4 v = *reinterpret_cast<const uint4*>(&V[base + (size_t)(kb + key) * HD_ + d8]);
                const unsigned short* e = reinterpret_cast<const unsigned short*>(&v);
                #pragma unroll
                for (int j = 0; j < 8; j++) {
                    const int i = (j + (tid & 7)) & 7;
                    Vts[(d8 + i) * ALD + key] = e[i];
                }
            }
        }
        if (tid < 64) mb[tid] = (1.f - (float)mask[b * S_ + kb + tid]) * (-10000.f);
        __syncthreads();

        // ---- S = Q @ K^T  (per wave)
        floatx4 sc[4];
        #pragma unroll
        for (int nt = 0; nt < 4; nt++) {
            const bf16x8 k0 = *reinterpret_cast<const bf16x8*>(&Ks[(nt * 16 + mrow) * ALD + koff]);
            const bf16x8 k1 = *reinterpret_cast<const bf16x8*>(&Ks[(nt * 16 + mrow) * ALD + 32 + koff]);
            floatx4 c = fzero4();
            c = __builtin_amdgcn_mfma_f32_16x16x32_bf16(qfrag0, k0, c, 0, 0, 0);
            c = __builtin_amdgcn_mfma_f32_16x16x32_bf16(qfrag1, k1, c, 0, 0, 0);
            sc[nt] = c;
        }

        // ---- online softmax
        float pv[4][4];
        float mtile[4];
        #pragma unroll
        for (int r = 0; r < 4; r++) mtile[r] = -1e30f;
        #pragma unroll
        for (int nt = 0; nt < 4; nt++) {
            const int key = kb + nt * 16 + col0;
            const float bias = mb[nt * 16 + col0];
            #pragma unroll
            for (int reg = 0; reg < 4; reg++) {
                const int q = qrow0 + r0 + reg;
                const float sv = (key <= q) ? (sc[nt][reg] * 0.125f + bias) : -10000.f;
                pv[nt][reg] = sv;
                mtile[reg] = fmaxf(mtile[reg], sv);
            }
        }
        #pragma unroll
        for (int off = 1; off < 16; off <<= 1)
            #pragma unroll
            for (int reg = 0; reg < 4; reg++)
                mtile[reg] = fmaxf(mtile[reg], __shfl_xor(mtile[reg], off, 64));

        float alpha[4], lsum[4];
        #pragma unroll
        for (int reg = 0; reg < 4; reg++) {
            const float mnew = fmaxf(m_i[reg], mtile[reg]);
            alpha[reg] = __expf(m_i[reg] - mnew);
            m_i[reg] = mnew;
            lsum[reg] = 0.f;
        }
        #pragma unroll
        for (int nt = 0; nt < 4; nt++)
            #pragma unroll
            for (int reg = 0; reg < 4; reg++) {
                const float p = __expf(pv[nt][reg] - m_i[reg]);
                pv[nt][reg] = p;
                lsum[reg] += p;
            }
        #pragma unroll
        for (int off = 1; off < 16; off <<= 1)
            #pragma unroll
            for (int reg = 0; reg < 4; reg++)
                lsum[reg] += __shfl_xor(lsum[reg], off, 64);
        #pragma unroll
        for (int reg = 0; reg < 4; reg++) l_i[reg] = l_i[reg] * alpha[reg] + lsum[reg];
        #pragma unroll
        for (int nt = 0; nt < 4; nt++)
            #pragma unroll
            for (int reg = 0; reg < 4; reg++) Oacc[nt][reg] *= alpha[reg];

        // ---- P -> LDS (C-layout to A-layout transform), then PV MFMA
        unsigned short* pw = Ps[wave];
        #pragma unroll
        for (int nt = 0; nt < 4; nt++)
            #pragma unroll
            for (int reg = 0; reg < 4; reg++)
                pw[(r0 + reg) * ALD + nt * 16 + col0] = f2bf_rn(pv[nt][reg]);

        const bf16x8 p0 = *reinterpret_cast<const bf16x8*>(&pw[mrow * ALD + koff]);
        const bf16x8 p1 = *reinterpret_cast<const bf16x8*>(&pw[mrow * ALD + 32 + koff]);
        #pragma unroll
        for (int nt = 0; nt < 4; nt++) {
            const bf16x8 v0 = *reinterpret_cast<const bf16x8*>(&Vts[(nt * 16 + col0) * ALD + koff]);
            const bf16x8 v1 = *reinterpret_cast<const bf16x8*>(&Vts[(nt * 16 + col0) * ALD + 32 + koff]);
            Oacc[nt] = __builtin_amdgcn_mfma_f32_16x16x32_bf16(p0, v0, Oacc[nt], 0, 0, 0);
            Oacc[nt] = __builtin_amdgcn_mfma_f32_16x16x32_bf16(p1, v1, Oacc[nt], 0, 0, 0);
        }
        __syncthreads();
    }

    // ---- epilogue: ctx[b][q][h*64+d] bf16
    float rl[4];
    #pragma unroll
    for (int reg = 0; reg < 4; reg++) rl[reg] = 1.f / l_i[reg];
    #pragma unroll
    for (int nt = 0; nt < 4; nt++)
        #pragma unroll
        for (int reg = 0; reg < 4; reg++) {
            const int q = qrow0 + r0 + reg;
            const int d = nt * 16 + col0;
            ctx[((size_t)b * S_ + q) * H_ + h * HD_ + d] = f2bf_rn(Oacc[nt][reg] * rl[reg]);
        }
}

// ---------------------------------------------------------------- launch
extern "C" void kernel_launch(void* const* d_in, const int* in_sizes, int n_in,
                              void* d_out, int out_size, void* d_ws, size_t ws_size,
                              hipStream_t stream) {
    const float* x     = (const float*)d_in[0];
    const int*   mask  = (const int*)d_in[1];
    const float* normw = (const float*)d_in[2];
    const float* normb = (const float*)d_in[3];
    const float* qkvw  = (const float*)d_in[4];
    const float* qkvb  = (const float*)d_in[5];
    const float* ow    = (const float*)d_in[6];
    const float* ob    = (const float*)d_in[7];
    float* out = (float*)d_out;

    char* ws = (char*)d_ws;
    unsigned short* xn_bf   = (unsigned short*)(ws);                      //  8 MB: T x H
    unsigned short* qkvw_bf = (unsigned short*)(ws + (8ull  << 20));      //  6 MB: H x 3H
    unsigned short* ow_bf   = (unsigned short*)(ws + (14ull << 20));      //  2 MB: H x H
    unsigned short* qkv_bf  = (unsigned short*)(ws + (16ull << 20));      // 24 MB: T x 3H
    unsigned short* Qb      = (unsigned short*)(ws + (40ull << 20));      //  8 MB
    unsigned short* Kb      = (unsigned short*)(ws + (48ull << 20));      //  8 MB
    unsigned short* Vb      = (unsigned short*)(ws + (56ull << 20));      //  8 MB
    unsigned short* ctx_bf  = (unsigned short*)(ws + (64ull << 20));      //  8 MB  (total 72 MB)

    cvt_bf16_k<<<(H_ * H3_ / 4 + 255) / 256, 256, 0, stream>>>(qkvw, qkvw_bf, H_ * H3_);
    cvt_bf16_k<<<(H_ * H_  / 4 + 255) / 256, 256, 0, stream>>>(ow,   ow_bf,   H_ * H_);
    layernorm_k<<<T_, 256, 0, stream>>>(x, normw, normb, xn_bf);
    gemm_bf16<false><<<dim3(H3_ / BN, T_ / BM), 256, 0, stream>>>(xn_bf, qkvw_bf, qkvb,
                                                                  nullptr, qkv_bf, T_, H3_, H_);
    rotary_scatter_k<<<T_, 256, 0, stream>>>(qkv_bf, Qb, Kb, Vb);
    attn_k<<<dim3(S_ / 64, B_ * NH_), 256, 0, stream>>>(Qb, Kb, Vb, mask, ctx_bf);
    gemm_bf16<true><<<dim3(H_ / BN, T_ / BM), 256, 0, stream>>>(ctx_bf, ow_bf, ob,
                                                                out, nullptr, T_, H_, H_);
}

// Round 2
// 347.015 us; speedup vs baseline: 1.2468x; 1.2468x over previous
//
#include <hip/hip_runtime.h>
#include <hip/hip_bf16.h>

#define B_  2
#define S_  2048
#define H_  1024
#define NH_ 16
#define HD_ 64
#define T_  (B_*S_)     // 4096 tokens
#define H3_ (3*H_)      // 3072

typedef float  floatx4 __attribute__((ext_vector_type(4)));
typedef __bf16 bf16x8  __attribute__((ext_vector_type(8)));

__device__ inline unsigned short f2bf_rn(float f) {
    union { float f; unsigned int u; } v; v.f = f;
    unsigned int u = v.u;
    u += 0x7fffu + ((u >> 16) & 1u);
    return (unsigned short)(u >> 16);
}
__device__ inline floatx4 fzero4() { floatx4 v; v[0]=0.f; v[1]=0.f; v[2]=0.f; v[3]=0.f; return v; }

// ---------------------------------------------------------------- fused cast + transpose: W[K][N] f32 -> Wt[N][K] bf16
#define TLD 72
__global__ __launch_bounds__(256) void cvt_transpose_k(const float* __restrict__ W,
                                                       unsigned short* __restrict__ Wt,
                                                       int K, int N) {
    __shared__ unsigned short Ts[64 * TLD];
    const int nb = blockIdx.x * 64;
    const int kb = blockIdx.y * 64;
    const int tid = threadIdx.x;
    #pragma unroll
    for (int p = 0; p < 4; p++) {
        const int krow = kb + p * 16 + (tid >> 4);
        const int ncol = (tid & 15) * 4;
        const float4 w = *reinterpret_cast<const float4*>(&W[(size_t)krow * N + nb + ncol]);
        Ts[(ncol + 0) * TLD + p * 16 + (tid >> 4)] = f2bf_rn(w.x);
        Ts[(ncol + 1) * TLD + p * 16 + (tid >> 4)] = f2bf_rn(w.y);
        Ts[(ncol + 2) * TLD + p * 16 + (tid >> 4)] = f2bf_rn(w.z);
        Ts[(ncol + 3) * TLD + p * 16 + (tid >> 4)] = f2bf_rn(w.w);
    }
    __syncthreads();
    #pragma unroll
    for (int p = 0; p < 2; p++) {
        const int n = (tid >> 3) + p * 32;
        const int k8 = (tid & 7) * 8;
        const uint4 v = *reinterpret_cast<const uint4*>(&Ts[n * TLD + k8]);
        *reinterpret_cast<uint4*>(&Wt[(size_t)(nb + n) * K + kb + k8]) = v;
    }
}

// ---------------------------------------------------------------- LayerNorm (fp32 stats, bf16 out)
__global__ __launch_bounds__(256) void layernorm_k(const float* __restrict__ x,
                                                   const float* __restrict__ w,
                                                   const float* __restrict__ b,
                                                   unsigned short* __restrict__ xn) {
    const int t   = blockIdx.x;
    const int tid = threadIdx.x;
    const float4 v = reinterpret_cast<const float4*>(x + (size_t)t * H_)[tid];
    float s  = v.x + v.y + v.z + v.w;
    float s2 = v.x*v.x + v.y*v.y + v.z*v.z + v.w*v.w;
    for (int off = 32; off > 0; off >>= 1) {
        s  += __shfl_down(s,  off, 64);
        s2 += __shfl_down(s2, off, 64);
    }
    __shared__ float red[8];
    const int wave = tid >> 6, lane = tid & 63;
    if (lane == 0) { red[wave] = s; red[4 + wave] = s2; }
    __syncthreads();
    if (tid == 0) {
        red[0] = red[0] + red[1] + red[2] + red[3];
        red[4] = red[4] + red[5] + red[6] + red[7];
    }
    __syncthreads();
    const float mean = red[0] * (1.f / H_);
    const float var  = red[4] * (1.f / H_) - mean * mean;
    const float rstd = rsqrtf(var + 1e-5f);
    const float4 wv = reinterpret_cast<const float4*>(w)[tid];
    const float4 bv = reinterpret_cast<const float4*>(b)[tid];
    ushort4 o = make_ushort4(f2bf_rn((v.x - mean) * rstd * wv.x + bv.x),
                             f2bf_rn((v.y - mean) * rstd * wv.y + bv.y),
                             f2bf_rn((v.z - mean) * rstd * wv.z + bv.z),
                             f2bf_rn((v.w - mean) * rstd * wv.w + bv.w));
    reinterpret_cast<ushort4*>(xn + (size_t)t * H_)[tid] = o;
}

// ---------------------------------------------------------------- bf16 MFMA GEMM  C = A(MxK) @ Bt(NxK)^T + bias
#define BM 128
#define BN 128
#define BK 32
#define LDT 40   // padded LDS stride: 80B = odd # of 16B superbanks, 16B aligned

template <bool OUT_F32>
__global__ __launch_bounds__(256, 2) void gemm_bf16(const unsigned short* __restrict__ A,
                                                    const unsigned short* __restrict__ Bt,
                                                    const float* __restrict__ bias,
                                                    float* __restrict__ Cf,
                                                    unsigned short* __restrict__ Cb,
                                                    int M, int N, int K) {
    __shared__ unsigned short As[BM * LDT];
    __shared__ unsigned short Bs[BN * LDT];   // Bs[n][k]

    const int tid  = threadIdx.x;
    const int lane = tid & 63;
    const int wave = tid >> 6;
    const int wr = wave >> 1, wc = wave & 1;
    const int mBase = blockIdx.y * BM;
    const int nBase = blockIdx.x * BN;

    floatx4 acc[4][4];
    #pragma unroll
    for (int i = 0; i < 4; i++)
        #pragma unroll
        for (int j = 0; j < 4; j++) acc[i][j] = fzero4();

    const int arow = tid >> 2;        // 0..63
    const int acol = (tid & 3) * 8;   // 0,8,16,24

    const int mrow = lane & 15;
    const int koff = (lane >> 4) * 8;

    for (int kb = 0; kb < K; kb += BK) {
        #pragma unroll
        for (int p = 0; p < 2; p++) {
            const int r = arow + p * 64;
            const uint4 va = *reinterpret_cast<const uint4*>(&A [(size_t)(mBase + r) * K + kb + acol]);
            const uint4 vb = *reinterpret_cast<const uint4*>(&Bt[(size_t)(nBase + r) * K + kb + acol]);
            *reinterpret_cast<uint4*>(&As[r * LDT + acol]) = va;
            *reinterpret_cast<uint4*>(&Bs[r * LDT + acol]) = vb;
        }
        __syncthreads();

        bf16x8 afrag[4], bfrag[4];
        #pragma unroll
        for (int mt = 0; mt < 4; mt++)
            afrag[mt] = *reinterpret_cast<const bf16x8*>(&As[(wr * 64 + mt * 16 + mrow) * LDT + koff]);
        #pragma unroll
        for (int nt = 0; nt < 4; nt++)
            bfrag[nt] = *reinterpret_cast<const bf16x8*>(&Bs[(wc * 64 + nt * 16 + mrow) * LDT + koff]);
        #pragma unroll
        for (int mt = 0; mt < 4; mt++)
            #pragma unroll
            for (int nt = 0; nt < 4; nt++)
                acc[mt][nt] = __builtin_amdgcn_mfma_f32_16x16x32_bf16(afrag[mt], bfrag[nt], acc[mt][nt], 0, 0, 0);
        __syncthreads();
    }

    const int col0 = lane & 15;
    const int r0   = (lane >> 4) * 4;
    #pragma unroll
    for (int mt = 0; mt < 4; mt++) {
        #pragma unroll
        for (int nt = 0; nt < 4; nt++) {
            const int gcol = nBase + wc * 64 + nt * 16 + col0;
            const float bs = bias[gcol];
            #pragma unroll
            for (int reg = 0; reg < 4; reg++) {
                const int grow = mBase + wr * 64 + mt * 16 + r0 + reg;
                const float v = acc[mt][nt][reg] + bs;
                if constexpr (OUT_F32) Cf[(size_t)grow * N + gcol] = v;
                else                   Cb[(size_t)grow * N + gcol] = f2bf_rn(v);
            }
        }
    }
}

// ---------------------------------------------------------------- rotary for q,k -> Q/K [b,h,s,d] bf16
__global__ __launch_bounds__(256) void rotary_qk_k(const unsigned short* __restrict__ qkv,
                                                   unsigned short* __restrict__ Q,
                                                   unsigned short* __restrict__ K) {
    const int t   = blockIdx.x;
    const int b   = t / S_;
    const int s   = t % S_;
    const int tid = threadIdx.x;
    const unsigned short* row = qkv + (size_t)t * H3_;
    #pragma unroll
    for (int i = 0; i < 4; i++) {
        const int idx = tid + i * 256;    // h*64 + d
        const int h = idx >> 6, d = idx & 63;
        const float inv_freq = __expf((float)(d & 31) * (-0.2878231366f)); // -ln(10000)/32
        const float fr = (float)s * inv_freq;
        float sn, cs;
        __sincosf(fr, &sn, &cs);
        const size_t dst = ((size_t)(b * NH_ + h) * S_ + s) * HD_ + d;
        {
            const float val = __builtin_amdgcn_ubfe(0,0,0), dummy = 0.f; (void)val; (void)dummy;
        }
        {
            union { unsigned int u; float f; } a, p;
            a.u = ((unsigned int)row[idx]) << 16;
            p.u = ((unsigned int)row[idx ^ 32]) << 16;
            const float rot = (d < 32) ? -p.f : p.f;
            Q[dst] = f2bf_rn(a.f * cs + rot * sn);
        }
        {
            union { unsigned int u; float f; } a, p;
            a.u = ((unsigned int)row[H_ + idx]) << 16;
            p.u = ((unsigned int)row[H_ + (idx ^ 32)]) << 16;
            const float rot = (d < 32) ? -p.f : p.f;
            K[dst] = f2bf_rn(a.f * cs + rot * sn);
        }
    }
}

// ---------------------------------------------------------------- V transpose: qkv v-part -> Vt[bh][d][s]
__global__ __launch_bounds__(256) void v_transpose_k(const unsigned short* __restrict__ qkv,
                                                     unsigned short* __restrict__ Vt) {
    __shared__ unsigned short Vs[64 * TLD];
    const int s0 = blockIdx.x * 64;
    const int b  = blockIdx.y;
    const int tid = threadIdx.x;
    for (int h = 0; h < NH_; h++) {
        __syncthreads();
        #pragma unroll
        for (int p = 0; p < 2; p++) {
            const int tl = tid >> 2;
            const int c  = (tid & 3) * 8 + p * 32;
            const uint4 v = *reinterpret_cast<const uint4*>(
                &qkv[(size_t)(b * S_ + s0 + tl) * H3_ + 2 * H_ + h * 64 + c]);
            *reinterpret_cast<uint4*>(&Vs[tl * TLD + c]) = v;
        }
        __syncthreads();
        #pragma unroll
        for (int p = 0; p < 2; p++) {
            const int d  = (tid >> 3) + p * 32;
            const int s8 = (tid & 7) * 8;
            unsigned short tmp[8];
            #pragma unroll
            for (int jj = 0; jj < 8; jj++) tmp[jj] = Vs[(s8 + jj) * TLD + d];
            *reinterpret_cast<uint4*>(&Vt[((size_t)(b * NH_ + h) * HD_ + d) * S_ + s0 + s8]) =
                *reinterpret_cast<uint4*>(tmp);
        }
    }
}

// ---------------------------------------------------------------- flash attention, band-paired for load balance
// block = 4 waves; bands j (kt<=j) and 31-j; wave owns 16 q-rows per band (2 m-tiles).
#define ALD 72

__global__ __launch_bounds__(256, 3) void attn_k(const unsigned short* __restrict__ Q,
                                                 const unsigned short* __restrict__ Kg,
                                                 const unsigned short* __restrict__ Vt,
                                                 const int* __restrict__ mask,
                                                 unsigned short* __restrict__ ctx) {
    const int j   = blockIdx.x;          // 0..15
    const int bh  = blockIdx.y;
    const int b   = bh >> 4;
    const int h   = bh & 15;
    const int tid = threadIdx.x;
    const int lane = tid & 63;
    const int wave = tid >> 6;

    __shared__ unsigned short Ks [64 * ALD];     // [key][hd]
    __shared__ unsigned short Vts[64 * ALD];     // [hd][key]
    __shared__ unsigned short Ps[4][32 * ALD];   // per-wave P

    const size_t base = (size_t)bh * S_ * HD_;
    const int qbase[2] = { j * 64 + wave * 16, (31 - j) * 64 + wave * 16 };
    const int mrow = lane & 15;
    const int koff = (lane >> 4) * 8;
    const int r0   = (lane >> 4) * 4;
    const int col0 = lane & 15;

    bf16x8 qf[2][2];
    #pragma unroll
    for (int m = 0; m < 2; m++)
        #pragma unroll
        for (int hh = 0; hh < 2; hh++)
            qf[m][hh] = *reinterpret_cast<const bf16x8*>(
                &Q[base + (size_t)(qbase[m] + mrow) * HD_ + hh * 32 + koff]);

    floatx4 Oacc[2][4];
    float m_i[2][4], l_i[2][4];
    #pragma unroll
    for (int m = 0; m < 2; m++) {
        #pragma unroll
        for (int nt = 0; nt < 4; nt++) Oacc[m][nt] = fzero4();
        #pragma unroll
        for (int r = 0; r < 4; r++) { m_i[m][r] = -1e30f; l_i[m][r] = 0.f; }
    }

    const int last = 31 - j;
    const int srow = tid >> 3;          // 0..31
    const int scol = (tid & 7) * 8;

    uint4 kreg[2], vreg[2];
    float mb_pf[4];
    auto prefetch = [&](int kt) {
        const int kb = kt * 64;
        #pragma unroll
        for (int p = 0; p < 2; p++) {
            kreg[p] = *reinterpret_cast<const uint4*>(&Kg[base + (size_t)(kb + srow + p * 32) * HD_ + scol]);
            vreg[p] = *reinterpret_cast<const uint4*>(&Vt[base + (size_t)(srow + p * 32) * S_ + kb + scol]);
        }
        #pragma unroll
        for (int nt = 0; nt < 4; nt++)
            mb_pf[nt] = (1.f - (float)mask[b * S_ + kb + nt * 16 + col0]) * (-10000.f);
    };
    prefetch(0);

    for (int kt = 0; kt <= last; kt++) {
        const int kb = kt * 64;
        __syncthreads();                               // prior iter's LDS reads done
        #pragma unroll
        for (int p = 0; p < 2; p++) {
            *reinterpret_cast<uint4*>(&Ks [(srow + p * 32) * ALD + scol]) = kreg[p];
            *reinterpret_cast<uint4*>(&Vts[(srow + p * 32) * ALD + scol]) = vreg[p];
        }
        __syncthreads();                               // staged tile visible
        float mb_c[4];
        #pragma unroll
        for (int nt = 0; nt < 4; nt++) mb_c[nt] = mb_pf[nt];
        if (kt < last) prefetch(kt + 1);

        const bool skip0 = (kt > j);

        bf16x8 kf[4][2];
        #pragma unroll
        for (int nt = 0; nt < 4; nt++) {
            kf[nt][0] = *reinterpret_cast<const bf16x8*>(&Ks[(nt * 16 + mrow) * ALD + koff]);
            kf[nt][1] = *reinterpret_cast<const bf16x8*>(&Ks[(nt * 16 + mrow) * ALD + 32 + koff]);
        }
        floatx4 sc[2][4];
        #pragma unroll
        for (int m = 0; m < 2; m++) {
            if (m == 0 && skip0) continue;
            #pragma unroll
            for (int nt = 0; nt < 4; nt++) {
                floatx4 c = fzero4();
                c = __builtin_amdgcn_mfma_f32_16x16x32_bf16(qf[m][0], kf[nt][0], c, 0, 0, 0);
                c = __builtin_amdgcn_mfma_f32_16x16x32_bf16(qf[m][1], kf[nt][1], c, 0, 0, 0);
                sc[m][nt] = c;
            }
        }

        #pragma unroll
        for (int m = 0; m < 2; m++) {
            if (m == 0 && skip0) continue;
            const bool needc = (kb + 63) > qbase[m];
            float mt[4];
            #pragma unroll
            for (int r = 0; r < 4; r++) mt[r] = -1e30f;
            #pragma unroll
            for (int nt = 0; nt < 4; nt++)
                #pragma unroll
                for (int reg = 0; reg < 4; reg++) {
                    float sv = sc[m][nt][reg] * 0.125f + mb_c[nt];
                    if (needc) {
                        const int key = kb + nt * 16 + col0;
                        const int q   = qbase[m] + r0 + reg;
                        if (key > q) sv = -10000.f;
                    }
                    sc[m][nt][reg] = sv;
                    mt[reg] = fmaxf(mt[reg], sv);
                }
            #pragma unroll
            for (int off = 1; off < 16; off <<= 1)
                #pragma unroll
                for (int reg = 0; reg < 4; reg++)
                    mt[reg] = fmaxf(mt[reg], __shfl_xor(mt[reg], off, 64));
            float alpha[4], ls[4];
            #pragma unroll
            for (int reg = 0; reg < 4; reg++) {
                const float mn = fmaxf(m_i[m][reg], mt[reg]);
                alpha[reg] = __expf(m_i[m][reg] - mn);
                m_i[m][reg] = mn;
                ls[reg] = 0.f;
            }
            unsigned short* pw = Ps[wave];
            #pragma unroll
            for (int nt = 0; nt < 4; nt++)
                #pragma unroll
                for (int reg = 0; reg < 4; reg++) {
                    const float p = __expf(sc[m][nt][reg] - m_i[m][reg]);
                    ls[reg] += p;
                    pw[(m * 16 + r0 + reg) * ALD + nt * 16 + col0] = f2bf_rn(p);
                }
            #pragma unroll
            for (int off = 1; off < 16; off <<= 1)
                #pragma unroll
                for (int reg = 0; reg < 4; reg++)
                    ls[reg] += __shfl_xor(ls[reg], off, 64);
            #pragma unroll
            for (int reg = 0; reg < 4; reg++) l_i[m][reg] = l_i[m][reg] * alpha[reg] + ls[reg];
            #pragma unroll
            for (int nt = 0; nt < 4; nt++)
                #pragma unroll
                for (int reg = 0; reg < 4; reg++) Oacc[m][nt][reg] *= alpha[reg];
        }

        bf16x8 vf[4][2];
        #pragma unroll
        for (int nt = 0; nt < 4; nt++) {
            vf[nt][0] = *reinterpret_cast<const bf16x8*>(&Vts[(nt * 16 + mrow) * ALD + koff]);
            vf[nt][1] = *reinterpret_cast<const bf16x8*>(&Vts[(nt * 16 + mrow) * ALD + 32 + koff]);
        }
        #pragma unroll
        for (int m = 0; m < 2; m++) {
            if (m == 0 && skip0) continue;
            const unsigned short* pw = Ps[wave];
            const bf16x8 p0 = *reinterpret_cast<const bf16x8*>(&pw[(m * 16 + mrow) * ALD + koff]);
            const bf16x8 p1 = *reinterpret_cast<const bf16x8*>(&pw[(m * 16 + mrow) * ALD + 32 + koff]);
            #pragma unroll
            for (int nt = 0; nt < 4; nt++) {
                Oacc[m][nt] = __builtin_amdgcn_mfma_f32_16x16x32_bf16(p0, vf[nt][0], Oacc[m][nt], 0, 0, 0);
                Oacc[m][nt] = __builtin_amdgcn_mfma_f32_16x16x32_bf16(p1, vf[nt][1], Oacc[m][nt], 0, 0, 0);
            }
        }
    }

    #pragma unroll
    for (int m = 0; m < 2; m++) {
        float rl[4];
        #pragma unroll
        for (int reg = 0; reg < 4; reg++) rl[reg] = 1.f / l_i[m][reg];
        #pragma unroll
        for (int nt = 0; nt < 4; nt++)
            #pragma unroll
            for (int reg = 0; reg < 4; reg++) {
                const int q = qbase[m] + r0 + reg;
                const int d = nt * 16 + col0;
                ctx[((size_t)b * S_ + q) * H_ + h * HD_ + d] = f2bf_rn(Oacc[m][nt][reg] * rl[reg]);
            }
    }
}

// ---------------------------------------------------------------- launch
extern "C" void kernel_launch(void* const* d_in, const int* in_sizes, int n_in,
                              void* d_out, int out_size, void* d_ws, size_t ws_size,
                              hipStream_t stream) {
    const float* x     = (const float*)d_in[0];
    const int*   mask  = (const int*)d_in[1];
    const float* normw = (const float*)d_in[2];
    const float* normb = (const float*)d_in[3];
    const float* qkvw  = (const float*)d_in[4];
    const float* qkvb  = (const float*)d_in[5];
    const float* ow    = (const float*)d_in[6];
    const float* ob    = (const float*)d_in[7];
    float* out = (float*)d_out;

    char* ws = (char*)d_ws;
    unsigned short* xn_bf   = (unsigned short*)(ws);                      //  8 MB: T x H
    unsigned short* qkvwT   = (unsigned short*)(ws + (8ull  << 20));      //  6 MB: 3H x H (transposed)
    unsigned short* owT     = (unsigned short*)(ws + (14ull << 20));      //  2 MB: H x H (transposed)
    unsigned short* qkv_bf  = (unsigned short*)(ws + (16ull << 20));      // 24 MB: T x 3H
    unsigned short* Qb      = (unsigned short*)(ws + (40ull << 20));      //  8 MB [bh][s][d]
    unsigned short* Kb      = (unsigned short*)(ws + (48ull << 20));      //  8 MB [bh][s][d]
    unsigned short* Vtb     = (unsigned short*)(ws + (56ull << 20));      //  8 MB [bh][d][s]
    unsigned short* ctx_bf  = (unsigned short*)(ws + (64ull << 20));      //  8 MB

    cvt_transpose_k<<<dim3(H3_ / 64, H_ / 64), 256, 0, stream>>>(qkvw, qkvwT, H_, H3_);
    cvt_transpose_k<<<dim3(H_  / 64, H_ / 64), 256, 0, stream>>>(ow,   owT,   H_, H_);
    layernorm_k<<<T_, 256, 0, stream>>>(x, normw, normb, xn_bf);
    gemm_bf16<false><<<dim3(H3_ / BN, T_ / BM), 256, 0, stream>>>(xn_bf, qkvwT, qkvb,
                                                                  nullptr, qkv_bf, T_, H3_, H_);
    rotary_qk_k<<<T_, 256, 0, stream>>>(qkv_bf, Qb, Kb);
    v_transpose_k<<<dim3(S_ / 64, B_), 256, 0, stream>>>(qkv_bf, Vtb);
    attn_k<<<dim3(16, B_ * NH_), 256, 0, stream>>>(Qb, Kb, Vtb, mask, ctx_bf);
    gemm_bf16<true><<<dim3(H_ / BN, T_ / BM), 256, 0, stream>>>(ctx_bf, owT, ob,
                                                                out, nullptr, T_, H_, H_);
}